// Round 6
// baseline (96.624 us; speedup 1.0000x reference)
//
#include <hip/hip_runtime.h>
#include <math.h>

#define BB 64
#define NN 2048
#define DD 128
#define KD 16
#define NORMF 0.25f
#define CHUNK 32
#define PSTRIDE 260                 // per-block partial: 2*DD + 2 + pad
#define WS_PART_OFF 64              // float offset; ws[0..64) = int counters

// wave-local LDS fence: DS ops within a wave are in-order; drain before cross-lane reads.
__device__ __forceinline__ void wave_lds_fence() {
    asm volatile("s_waitcnt lgkmcnt(0)" ::: "memory");
    __builtin_amdgcn_wave_barrier();
}

// ---------------- single fused kernel ----------------
// grid = BB*P blocks x 256 threads. Each block: w-prologue, K=16/P chunks per wave,
// block partial -> ws; last block per batch runs the Wv/Wo finalize.
template <int P>
__global__ __launch_bounds__(256)
void attn_all(const float* __restrict__ h,
              const float* __restrict__ adj,
              const int*   __restrict__ phone,
              const float* __restrict__ Wq_bf, const float* __restrict__ Wk_bf,
              const float* __restrict__ Wv_bf, const float* __restrict__ Wo_bf,
              const float* __restrict__ Wq_af, const float* __restrict__ Wk_af,
              const float* __restrict__ Wv_af, const float* __restrict__ Wo_af,
              float* __restrict__ ws)
{
    constexpr int K = 16 / P;          // chunks per wave
    const int tid  = threadIdx.x;
    const int wid  = tid >> 6;
    const int lane = tid & 63;
    const int half = lane >> 5;
    const int l    = lane & 31;
    const int dbase = 4 * l;

    // XCD swizzle: all P blocks of a batch on one XCD (adj row / weights / partials L2-local)
    const int xcd  = blockIdx.x & 7;
    const int slot = blockIdx.x >> 3;
    const int b    = xcd + 8 * (slot / P);
    const int bip  = slot % P;
    const int ph   = phone[b];

    int* __restrict__ cnt = (int*)ws;
    float* __restrict__ wpart = ws + WS_PART_OFF;

    __shared__ float hp[DD];
    __shared__ float qpart[32][8];
    __shared__ float q[2][KD];
    __shared__ float w_s[2][DD];
    __shared__ float part[4][CHUNK][33];
    __shared__ float ea_s[4][CHUNK];
    __shared__ float red_h[4][2][DD];
    __shared__ float red_s[4][2];
    __shared__ int   isLast;

    const float* hb     = h + (size_t)b * NN * DD;
    const float* adjrow = adj + ((size_t)b * NN + ph) * NN;
    const int chbase    = (bip * 4 + wid) * K;

    // ---- issue adj loads first; w-prologue executes under their latency
    float adjv[K];
    #pragma unroll
    for (int c = 0; c < K; ++c) adjv[c] = adjrow[(chbase + c) * CHUNK + l];

    if (tid < DD) hp[tid] = hb[(size_t)ph * DD + tid];
    __syncthreads();

    {   // q partials: 8 threads per (br,k)
        const int pair = tid >> 3, sub = tid & 7;
        const int br = pair >> 4, k = pair & 15;
        const float* Wq = br ? Wq_af : Wq_bf;
        float acc = 0.f;
        #pragma unroll
        for (int i = 0; i < 16; ++i) {
            const int d = sub * 16 + i;
            acc += hp[d] * Wq[d * KD + k];
        }
        qpart[pair][sub] = acc;
    }
    __syncthreads();
    if (tid < 32) {
        float acc = 0.f;
        #pragma unroll
        for (int i = 0; i < 8; ++i) acc += qpart[tid][i];
        q[tid >> 4][tid & 15] = acc;
    }
    __syncthreads();
    {   // w: one thread per (br,d)
        const int br = tid >> 7, d = tid & 127;
        const float* Wk = br ? Wk_af : Wk_bf;
        float acc = 0.f;
        #pragma unroll
        for (int k = 0; k < KD; ++k) acc += Wk[d * KD + k] * q[br][k];
        w_s[br][d] = NORMF * acc;
    }
    __syncthreads();

    const float4 wbf = *(const float4*)(&w_s[0][dbase]);
    const float4 waf = *(const float4*)(&w_s[1][dbase]);

    float sbf = 0.f, saf = 0.f;
    float hgbf[4] = {0, 0, 0, 0}, hgaf[4] = {0, 0, 0, 0};

    #pragma unroll
    for (int c = 0; c < K; ++c) {
        const int n0 = (chbase + c) * CHUNK;
        const unsigned long long mask = __ballot(adjv[c] != 0.f);  // bits 0..31 = rows

        float4 hv[16];
        #pragma unroll
        for (int t = 0; t < 16; ++t) {
            const int r = 2 * t + half;
            hv[t] = make_float4(0.f, 0.f, 0.f, 0.f);
            if ((mask >> r) & 1ull)
                hv[t] = *(const float4*)(hb + (size_t)(n0 + r) * DD + dbase);
        }

        // phase A: per-lane partial dots -> LDS transpose (wave-private)
        #pragma unroll
        for (int t = 0; t < 16; ++t) {
            const int r = 2 * t + half;
            const float4 w = ((n0 + r) >= ph) ? waf : wbf;
            part[wid][r][l] = hv[t].x * w.x + hv[t].y * w.y + hv[t].z * w.z + hv[t].w * w.w;
        }
        wave_lds_fence();

        // phase B: one row per lane (halves duplicate rows 0..31)
        float a0 = 0.f, a1 = 0.f, a2 = 0.f, a3 = 0.f;
        #pragma unroll
        for (int j = 0; j < 32; j += 4) {
            a0 += part[wid][l][j];
            a1 += part[wid][l][j + 1];
            a2 += part[wid][l][j + 2];
            a3 += part[wid][l][j + 3];
        }
        const float p = (a0 + a1) + (a2 + a3);
        const float e = __expf(10.f * tanhf(p) - 10.f);   // fixed max: compat in (-10,10)
        const float es = (adjv[c] != 0.f) ? e : 0.f;
        const float ea = es * adjv[c];
        const bool rowaf = (n0 + l) >= ph;
        sbf += rowaf ? 0.f : es;
        saf += rowaf ? es : 0.f;
        if (lane < 32) ea_s[wid][l] = ea;
        wave_lds_fence();

        // phase C: weighted accumulation from registers
        #pragma unroll
        for (int t = 0; t < 16; ++t) {
            const int r = 2 * t + half;
            const float ear = ea_s[wid][r];               // broadcast read
            const bool af = (n0 + r) >= ph;
            const float eb = af ? 0.f : ear;
            const float ef = af ? ear : 0.f;
            hgbf[0] += eb * hv[t].x; hgbf[1] += eb * hv[t].y;
            hgbf[2] += eb * hv[t].z; hgbf[3] += eb * hv[t].w;
            hgaf[0] += ef * hv[t].x; hgaf[1] += ef * hv[t].y;
            hgaf[2] += ef * hv[t].z; hgaf[3] += ef * hv[t].w;
        }
    }

    // ---- per-wave reductions
    #pragma unroll
    for (int m = 1; m <= 16; m <<= 1) {
        sbf += __shfl_xor(sbf, m, 64);
        saf += __shfl_xor(saf, m, 64);
    }
    #pragma unroll
    for (int i = 0; i < 4; ++i) {
        hgbf[i] += __shfl_xor(hgbf[i], 32, 64);   // combine halves (same d-range)
        hgaf[i] += __shfl_xor(hgaf[i], 32, 64);
    }
    if (lane < 32) {
        #pragma unroll
        for (int i = 0; i < 4; ++i) {
            red_h[wid][0][dbase + i] = hgbf[i];
            red_h[wid][1][dbase + i] = hgaf[i];
        }
    }
    if (lane == 0) { red_s[wid][0] = sbf; red_s[wid][1] = saf; }
    __syncthreads();

    {   // block partial -> ws (coalesced, no atomics)
        const int br = tid >> 7, d = tid & 127;
        float* op = wpart + (size_t)(b * P + bip) * PSTRIDE;
        op[br * DD + d] = red_h[0][br][d] + red_h[1][br][d] + red_h[2][br][d] + red_h[3][br][d];
        if (tid < 2)
            op[2 * DD + tid] = red_s[0][tid] + red_s[1][tid] + red_s[2][tid] + red_s[3][tid];
    }
    __threadfence();            // release partial stores to device scope
    __syncthreads();            // all threads' fences done before the count
    if (tid == 0) {
        const int prev = atomicAdd(&cnt[b], 1);   // device-scope RMW
        isLast = (prev == P - 1) ? 1 : 0;
    }
    __syncthreads();
    if (!isLast) return;

    // ================= finalize (exactly one block per batch) =================
    __threadfence();            // acquire other blocks' partials

    __shared__ float hs[2][DD];
    __shared__ float ssum[2];
    __shared__ float hpart[32][8];
    __shared__ float head[2][KD];

    const float* base = wpart + (size_t)b * P * PSTRIDE;
    {
        const int br = tid >> 7, d = tid & 127;
        float acc = 0.f;
        #pragma unroll
        for (int p = 0; p < P; ++p) acc += base[(size_t)p * PSTRIDE + br * DD + d];
        hs[br][d] = acc;
    }
    if (tid < 2) {
        float acc = 0.f;
        #pragma unroll
        for (int p = 0; p < P; ++p) acc += base[(size_t)p * PSTRIDE + 2 * DD + tid];
        ssum[tid] = acc;
    }
    __syncthreads();

    {   // head partials: 8 threads per (br,k)
        const int pair = tid >> 3, sub = tid & 7;
        const int br = pair >> 4, k = pair & 15;
        const float* Wv = br ? Wv_af : Wv_bf;
        float acc = 0.f;
        #pragma unroll
        for (int i = 0; i < 16; ++i) {
            const int d = sub * 16 + i;
            acc += hs[br][d] * Wv[d * KD + k];
        }
        hpart[pair][sub] = acc;
    }
    __syncthreads();
    if (tid < 32) {
        float acc = 0.f;
        #pragma unroll
        for (int i = 0; i < 8; ++i) acc += hpart[tid][i];
        head[tid >> 4][tid & 15] = acc;
    }
    __syncthreads();

    {
        float* out = (float*)0;  // placeholder removed below
    }
    // out pointer passed via ws? no — passed as arg; see below
}

// NOTE: out is needed in finalize; wrap with a second parameter-carrying version.
// (The actual kernel used is attn_all_out below; attn_all kept minimal above was
// refactored — single definitive kernel follows.)

template <int P>
__global__ __launch_bounds__(256)
void attn_full(const float* __restrict__ h,
               const float* __restrict__ adj,
               const int*   __restrict__ phone,
               const float* __restrict__ Wq_bf, const float* __restrict__ Wk_bf,
               const float* __restrict__ Wv_bf, const float* __restrict__ Wo_bf,
               const float* __restrict__ Wq_af, const float* __restrict__ Wk_af,
               const float* __restrict__ Wv_af, const float* __restrict__ Wo_af,
               float* __restrict__ ws, float* __restrict__ out)
{
    constexpr int K = 16 / P;
    const int tid  = threadIdx.x;
    const int wid  = tid >> 6;
    const int lane = tid & 63;
    const int half = lane >> 5;
    const int l    = lane & 31;
    const int dbase = 4 * l;

    const int xcd  = blockIdx.x & 7;
    const int slot = blockIdx.x >> 3;
    const int b    = xcd + 8 * (slot / P);
    const int bip  = slot % P;
    const int ph   = phone[b];

    int* __restrict__ cnt = (int*)ws;
    float* __restrict__ wpart = ws + WS_PART_OFF;

    __shared__ float hp[DD];
    __shared__ float qpart[32][8];
    __shared__ float q[2][KD];
    __shared__ float w_s[2][DD];
    __shared__ float part[4][CHUNK][33];
    __shared__ float ea_s[4][CHUNK];
    __shared__ float red_h[4][2][DD];
    __shared__ float red_s[4][2];
    __shared__ int   isLast;

    const float* hb     = h + (size_t)b * NN * DD;
    const float* adjrow = adj + ((size_t)b * NN + ph) * NN;
    const int chbase    = (bip * 4 + wid) * K;

    float adjv[K];
    #pragma unroll
    for (int c = 0; c < K; ++c) adjv[c] = adjrow[(chbase + c) * CHUNK + l];

    if (tid < DD) hp[tid] = hb[(size_t)ph * DD + tid];
    __syncthreads();

    {
        const int pair = tid >> 3, sub = tid & 7;
        const int br = pair >> 4, k = pair & 15;
        const float* Wq = br ? Wq_af : Wq_bf;
        float acc = 0.f;
        #pragma unroll
        for (int i = 0; i < 16; ++i) {
            const int d = sub * 16 + i;
            acc += hp[d] * Wq[d * KD + k];
        }
        qpart[pair][sub] = acc;
    }
    __syncthreads();
    if (tid < 32) {
        float acc = 0.f;
        #pragma unroll
        for (int i = 0; i < 8; ++i) acc += qpart[tid][i];
        q[tid >> 4][tid & 15] = acc;
    }
    __syncthreads();
    {
        const int br = tid >> 7, d = tid & 127;
        const float* Wk = br ? Wk_af : Wk_bf;
        float acc = 0.f;
        #pragma unroll
        for (int k = 0; k < KD; ++k) acc += Wk[d * KD + k] * q[br][k];
        w_s[br][d] = NORMF * acc;
    }
    __syncthreads();

    const float4 wbf = *(const float4*)(&w_s[0][dbase]);
    const float4 waf = *(const float4*)(&w_s[1][dbase]);

    float sbf = 0.f, saf = 0.f;
    float hgbf[4] = {0, 0, 0, 0}, hgaf[4] = {0, 0, 0, 0};

    #pragma unroll
    for (int c = 0; c < K; ++c) {
        const int n0 = (chbase + c) * CHUNK;
        const unsigned long long mask = __ballot(adjv[c] != 0.f);

        float4 hv[16];
        #pragma unroll
        for (int t = 0; t < 16; ++t) {
            const int r = 2 * t + half;
            hv[t] = make_float4(0.f, 0.f, 0.f, 0.f);
            if ((mask >> r) & 1ull)
                hv[t] = *(const float4*)(hb + (size_t)(n0 + r) * DD + dbase);
        }

        #pragma unroll
        for (int t = 0; t < 16; ++t) {
            const int r = 2 * t + half;
            const float4 w = ((n0 + r) >= ph) ? waf : wbf;
            part[wid][r][l] = hv[t].x * w.x + hv[t].y * w.y + hv[t].z * w.z + hv[t].w * w.w;
        }
        wave_lds_fence();

        float a0 = 0.f, a1 = 0.f, a2 = 0.f, a3 = 0.f;
        #pragma unroll
        for (int j = 0; j < 32; j += 4) {
            a0 += part[wid][l][j];
            a1 += part[wid][l][j + 1];
            a2 += part[wid][l][j + 2];
            a3 += part[wid][l][j + 3];
        }
        const float p = (a0 + a1) + (a2 + a3);
        const float e = __expf(10.f * tanhf(p) - 10.f);
        const float es = (adjv[c] != 0.f) ? e : 0.f;
        const float ea = es * adjv[c];
        const bool rowaf = (n0 + l) >= ph;
        sbf += rowaf ? 0.f : es;
        saf += rowaf ? es : 0.f;
        if (lane < 32) ea_s[wid][l] = ea;
        wave_lds_fence();

        #pragma unroll
        for (int t = 0; t < 16; ++t) {
            const int r = 2 * t + half;
            const float ear = ea_s[wid][r];
            const bool af = (n0 + r) >= ph;
            const float eb = af ? 0.f : ear;
            const float ef = af ? ear : 0.f;
            hgbf[0] += eb * hv[t].x; hgbf[1] += eb * hv[t].y;
            hgbf[2] += eb * hv[t].z; hgbf[3] += eb * hv[t].w;
            hgaf[0] += ef * hv[t].x; hgaf[1] += ef * hv[t].y;
            hgaf[2] += ef * hv[t].z; hgaf[3] += ef * hv[t].w;
        }
    }

    #pragma unroll
    for (int m = 1; m <= 16; m <<= 1) {
        sbf += __shfl_xor(sbf, m, 64);
        saf += __shfl_xor(saf, m, 64);
    }
    #pragma unroll
    for (int i = 0; i < 4; ++i) {
        hgbf[i] += __shfl_xor(hgbf[i], 32, 64);
        hgaf[i] += __shfl_xor(hgaf[i], 32, 64);
    }
    if (lane < 32) {
        #pragma unroll
        for (int i = 0; i < 4; ++i) {
            red_h[wid][0][dbase + i] = hgbf[i];
            red_h[wid][1][dbase + i] = hgaf[i];
        }
    }
    if (lane == 0) { red_s[wid][0] = sbf; red_s[wid][1] = saf; }
    __syncthreads();

    {
        const int br = tid >> 7, d = tid & 127;
        float* op = wpart + (size_t)(b * P + bip) * PSTRIDE;
        op[br * DD + d] = red_h[0][br][d] + red_h[1][br][d] + red_h[2][br][d] + red_h[3][br][d];
        if (tid < 2)
            op[2 * DD + tid] = red_s[0][tid] + red_s[1][tid] + red_s[2][tid] + red_s[3][tid];
    }
    __threadfence();
    __syncthreads();
    if (tid == 0) {
        const int prev = atomicAdd(&cnt[b], 1);
        isLast = (prev == P - 1) ? 1 : 0;
    }
    __syncthreads();
    if (!isLast) return;

    // ---- finalize: exactly one block per batch ----
    __threadfence();

    __shared__ float hs[2][DD];
    __shared__ float ssum[2];
    __shared__ float hpart2[32][8];
    __shared__ float head[2][KD];

    const float* base = wpart + (size_t)b * P * PSTRIDE;
    {
        const int br = tid >> 7, d = tid & 127;
        float acc = 0.f;
        #pragma unroll
        for (int p = 0; p < P; ++p) acc += base[(size_t)p * PSTRIDE + br * DD + d];
        hs[br][d] = acc;
    }
    if (tid < 2) {
        float acc = 0.f;
        #pragma unroll
        for (int p = 0; p < P; ++p) acc += base[(size_t)p * PSTRIDE + 2 * DD + tid];
        ssum[tid] = acc;
    }
    __syncthreads();

    {
        const int pair = tid >> 3, sub = tid & 7;
        const int br = pair >> 4, k = pair & 15;
        const float* Wv = br ? Wv_af : Wv_bf;
        float acc = 0.f;
        #pragma unroll
        for (int i = 0; i < 16; ++i) {
            const int d = sub * 16 + i;
            acc += hs[br][d] * Wv[d * KD + k];
        }
        hpart2[pair][sub] = acc;
    }
    __syncthreads();
    if (tid < 32) {
        float acc = 0.f;
        #pragma unroll
        for (int i = 0; i < 8; ++i) acc += hpart2[tid][i];
        head[tid >> 4][tid & 15] = acc;
    }
    __syncthreads();

    {
        const int br = tid >> 7, j = tid & 127;
        const float s = ssum[br];
        const float inv = (s > 0.f) ? 1.f / s : 0.f;
        const float* Wo = br ? Wo_af : Wo_bf;
        float acc = 0.f;
        #pragma unroll
        for (int k = 0; k < KD; ++k) acc += head[br][k] * Wo[k * DD + j];
        out[br * BB * DD + b * DD + j] = acc * inv;
    }
}

extern "C" void kernel_launch(void* const* d_in, const int* in_sizes, int n_in,
                              void* d_out, int out_size, void* d_ws, size_t ws_size,
                              hipStream_t stream) {
    const float* h     = (const float*)d_in[0];
    const float* adj   = (const float*)d_in[1];
    const int*   phone = (const int*)d_in[2];
    const float* Wq_bf = (const float*)d_in[3];
    const float* Wk_bf = (const float*)d_in[4];
    const float* Wv_bf = (const float*)d_in[5];
    const float* Wo_bf = (const float*)d_in[6];
    const float* Wq_af = (const float*)d_in[7];
    const float* Wk_af = (const float*)d_in[8];
    const float* Wv_af = (const float*)d_in[9];
    const float* Wo_af = (const float*)d_in[10];

    float* out = (float*)d_out;
    float* ws  = (float*)d_ws;

    int P = 16;
    while (P > 1 &&
           (size_t)(WS_PART_OFF + (size_t)BB * P * PSTRIDE) * sizeof(float) > ws_size)
        P >>= 1;

    // zero the per-batch completion counters (captured as a graph node)
    hipMemsetAsync(ws, 0, WS_PART_OFF * sizeof(float), stream);

    switch (P) {
    case 16: attn_full<16><<<BB * 16, 256, 0, stream>>>(h, adj, phone, Wq_bf, Wk_bf, Wv_bf, Wo_bf,
                                                        Wq_af, Wk_af, Wv_af, Wo_af, ws, out); break;
    case 8:  attn_full<8><<<BB * 8, 256, 0, stream>>>(h, adj, phone, Wq_bf, Wk_bf, Wv_bf, Wo_bf,
                                                      Wq_af, Wk_af, Wv_af, Wo_af, ws, out); break;
    case 4:  attn_full<4><<<BB * 4, 256, 0, stream>>>(h, adj, phone, Wq_bf, Wk_bf, Wv_bf, Wo_bf,
                                                      Wq_af, Wk_af, Wv_af, Wo_af, ws, out); break;
    case 2:  attn_full<2><<<BB * 2, 256, 0, stream>>>(h, adj, phone, Wq_bf, Wk_bf, Wv_bf, Wo_bf,
                                                      Wq_af, Wk_af, Wv_af, Wo_af, ws, out); break;
    default: attn_full<1><<<BB, 256, 0, stream>>>(h, adj, phone, Wq_bf, Wk_bf, Wv_bf, Wo_bf,
                                                  Wq_af, Wk_af, Wv_af, Wo_af, ws, out); break;
    }
}

// Round 7
// 19.167 us; speedup vs baseline: 5.0412x; 5.0412x over previous
//
#include <hip/hip_runtime.h>
#include <math.h>

#define BB 64
#define NN 2048
#define DD 128
#define KD 16
#define NORMF 0.25f
#define CHUNK 32
#define PSTRIDE 260                 // per-block partial: 2*DD + 2 + pad

// wave-local LDS fence: DS ops within a wave are in-order; drain before cross-lane reads.
__device__ __forceinline__ void wave_lds_fence() {
    asm volatile("s_waitcnt lgkmcnt(0)" ::: "memory");
    __builtin_amdgcn_wave_barrier();
}

// ---------------- main: w-prologue + masked streaming over h, partials -> ws ----------------
template <int P>
__global__ __launch_bounds__(256)
void attn_main(const float* __restrict__ h,
               const float* __restrict__ adj,
               const int*   __restrict__ phone,
               const float* __restrict__ Wq_bf, const float* __restrict__ Wk_bf,
               const float* __restrict__ Wq_af, const float* __restrict__ Wk_af,
               float* __restrict__ ws)
{
    constexpr int K = 16 / P;          // chunks per wave
    const int tid  = threadIdx.x;
    const int wid  = tid >> 6;
    const int lane = tid & 63;
    const int half = lane >> 5;
    const int l    = lane & 31;
    const int dbase = 4 * l;

    // XCD swizzle: all P blocks of a batch on one XCD (adj row / h_phone / weights L2-local)
    const int xcd  = blockIdx.x & 7;
    const int slot = blockIdx.x >> 3;
    const int b    = xcd + 8 * (slot / P);
    const int bip  = slot % P;
    const int ph   = phone[b];

    __shared__ float hp[DD];
    __shared__ float qpart[32][8];
    __shared__ float q[2][KD];
    __shared__ float w_s[2][DD];
    __shared__ float part[4][CHUNK][33];
    __shared__ float ea_s[4][CHUNK];
    __shared__ float red_h[4][2][DD];
    __shared__ float red_s[4][2];

    const float* hb     = h + (size_t)b * NN * DD;
    const float* adjrow = adj + ((size_t)b * NN + ph) * NN;
    const int chbase    = (bip * 4 + wid) * K;

    // ---- issue adj loads first; entire w-prologue runs under their latency
    float adjv[K];
    #pragma unroll
    for (int c = 0; c < K; ++c) adjv[c] = adjrow[(chbase + c) * CHUNK + l];

    if (tid < DD) hp[tid] = hb[(size_t)ph * DD + tid];
    __syncthreads();

    {   // q partials: 8 threads per (br,k)
        const int pair = tid >> 3, sub = tid & 7;
        const int br = pair >> 4, k = pair & 15;
        const float* Wq = br ? Wq_af : Wq_bf;
        float acc = 0.f;
        #pragma unroll
        for (int i = 0; i < 16; ++i) {
            const int d = sub * 16 + i;
            acc += hp[d] * Wq[d * KD + k];
        }
        qpart[pair][sub] = acc;
    }
    __syncthreads();
    if (tid < 32) {
        float acc = 0.f;
        #pragma unroll
        for (int i = 0; i < 8; ++i) acc += qpart[tid][i];
        q[tid >> 4][tid & 15] = acc;
    }
    __syncthreads();
    {   // w: one thread per (br,d)
        const int br = tid >> 7, d = tid & 127;
        const float* Wk = br ? Wk_af : Wk_bf;
        float acc = 0.f;
        #pragma unroll
        for (int k = 0; k < KD; ++k) acc += Wk[d * KD + k] * q[br][k];
        w_s[br][d] = NORMF * acc;
    }
    __syncthreads();

    const float4 wbf = *(const float4*)(&w_s[0][dbase]);
    const float4 waf = *(const float4*)(&w_s[1][dbase]);

    float sbf = 0.f, saf = 0.f;
    float hgbf[4] = {0, 0, 0, 0}, hgaf[4] = {0, 0, 0, 0};

    #pragma unroll
    for (int c = 0; c < K; ++c) {
        const int n0 = (chbase + c) * CHUNK;
        const unsigned long long mask = __ballot(adjv[c] != 0.f);  // bits 0..31 = rows

        float4 hv[16];
        #pragma unroll
        for (int t = 0; t < 16; ++t) {
            const int r = 2 * t + half;
            hv[t] = make_float4(0.f, 0.f, 0.f, 0.f);
            if ((mask >> r) & 1ull)
                hv[t] = *(const float4*)(hb + (size_t)(n0 + r) * DD + dbase);
        }

        // phase A: per-lane partial dots -> LDS transpose (wave-private)
        #pragma unroll
        for (int t = 0; t < 16; ++t) {
            const int r = 2 * t + half;
            const float4 w = ((n0 + r) >= ph) ? waf : wbf;
            part[wid][r][l] = hv[t].x * w.x + hv[t].y * w.y + hv[t].z * w.z + hv[t].w * w.w;
        }
        wave_lds_fence();

        // phase B: one row per lane (halves duplicate rows 0..31)
        float a0 = 0.f, a1 = 0.f, a2 = 0.f, a3 = 0.f;
        #pragma unroll
        for (int j = 0; j < 32; j += 4) {
            a0 += part[wid][l][j];
            a1 += part[wid][l][j + 1];
            a2 += part[wid][l][j + 2];
            a3 += part[wid][l][j + 3];
        }
        const float p = (a0 + a1) + (a2 + a3);
        const float e = __expf(10.f * tanhf(p) - 10.f);   // fixed max: compat in (-10,10)
        const float es = (adjv[c] != 0.f) ? e : 0.f;
        const float ea = es * adjv[c];
        const bool rowaf = (n0 + l) >= ph;
        sbf += rowaf ? 0.f : es;
        saf += rowaf ? es : 0.f;
        if (lane < 32) ea_s[wid][l] = ea;
        wave_lds_fence();

        // phase C: weighted accumulation from registers
        #pragma unroll
        for (int t = 0; t < 16; ++t) {
            const int r = 2 * t + half;
            const float ear = ea_s[wid][r];               // broadcast read
            const bool af = (n0 + r) >= ph;
            const float eb = af ? 0.f : ear;
            const float ef = af ? ear : 0.f;
            hgbf[0] += eb * hv[t].x; hgbf[1] += eb * hv[t].y;
            hgbf[2] += eb * hv[t].z; hgbf[3] += eb * hv[t].w;
            hgaf[0] += ef * hv[t].x; hgaf[1] += ef * hv[t].y;
            hgaf[2] += ef * hv[t].z; hgaf[3] += ef * hv[t].w;
        }
    }

    // ---- per-wave reductions
    #pragma unroll
    for (int m = 1; m <= 16; m <<= 1) {
        sbf += __shfl_xor(sbf, m, 64);
        saf += __shfl_xor(saf, m, 64);
    }
    #pragma unroll
    for (int i = 0; i < 4; ++i) {
        hgbf[i] += __shfl_xor(hgbf[i], 32, 64);   // combine halves (same d-range)
        hgaf[i] += __shfl_xor(hgaf[i], 32, 64);
    }
    if (lane < 32) {
        #pragma unroll
        for (int i = 0; i < 4; ++i) {
            red_h[wid][0][dbase + i] = hgbf[i];
            red_h[wid][1][dbase + i] = hgaf[i];
        }
    }
    if (lane == 0) { red_s[wid][0] = sbf; red_s[wid][1] = saf; }
    __syncthreads();   // the only cross-wave exchange

    {   // block partial -> ws (coalesced, no atomics, no fences)
        const int br = tid >> 7, d = tid & 127;
        float* op = ws + (size_t)(b * P + bip) * PSTRIDE;
        op[br * DD + d] = red_h[0][br][d] + red_h[1][br][d] + red_h[2][br][d] + red_h[3][br][d];
        if (tid < 2)
            op[2 * DD + tid] = red_s[0][tid] + red_s[1][tid] + red_s[2][tid] + red_s[3][tid];
    }
}

// ---------------- finalize: reduce P partials, head = hagg@Wv, out = (head@Wo)/s ----
// All weight loads hoisted to kernel start so they overlap the partial loads.
template <int P>
__global__ __launch_bounds__(256)
void finalize_kernel(const float* __restrict__ Wv_bf, const float* __restrict__ Wo_bf,
                     const float* __restrict__ Wv_af, const float* __restrict__ Wo_af,
                     const float* __restrict__ ws, float* __restrict__ out)
{
    const int b = blockIdx.x;
    const int tid = threadIdx.x;
    __shared__ float hs[2][DD];
    __shared__ float ssum[2];
    __shared__ float hpart[32][8];
    __shared__ float head[2][KD];

    // ---- issue ALL independent loads up front
    // Wv slice for the head-GEMV (thread role: pair=(br,k), sub)
    const int pair = tid >> 3, sub = tid & 7;
    const int brv = pair >> 4, kv = pair & 15;
    const float* Wv = brv ? Wv_af : Wv_bf;
    float wvr[16];
    #pragma unroll
    for (int i = 0; i < 16; ++i) wvr[i] = Wv[(sub * 16 + i) * KD + kv];

    // Wo slice for the out-GEMV (thread role: br2, j)
    const int br2 = tid >> 7, j = tid & 127;
    const float* Wo = br2 ? Wo_af : Wo_bf;
    float wor[KD];
    #pragma unroll
    for (int k = 0; k < KD; ++k) wor[k] = Wo[k * DD + j];

    // partial sums (16 independent loads each)
    const float* base = ws + (size_t)b * P * PSTRIDE;
    {
        float acc = 0.f;
        #pragma unroll
        for (int p = 0; p < P; ++p) acc += base[(size_t)p * PSTRIDE + br2 * DD + j];
        hs[br2][j] = acc;
    }
    if (tid < 2) {
        float acc = 0.f;
        #pragma unroll
        for (int p = 0; p < P; ++p) acc += base[(size_t)p * PSTRIDE + 2 * DD + tid];
        ssum[tid] = acc;
    }
    __syncthreads();

    {   // head partials from preloaded Wv
        float acc = 0.f;
        #pragma unroll
        for (int i = 0; i < 16; ++i) acc += hs[brv][sub * 16 + i] * wvr[i];
        hpart[pair][sub] = acc;
    }
    __syncthreads();
    if (tid < 32) {
        float acc = 0.f;
        #pragma unroll
        for (int i = 0; i < 8; ++i) acc += hpart[tid][i];
        head[tid >> 4][tid & 15] = acc;
    }
    __syncthreads();

    {   // out from preloaded Wo
        const float s = ssum[br2];
        const float inv = (s > 0.f) ? 1.f / s : 0.f;
        float acc = 0.f;
        #pragma unroll
        for (int k = 0; k < KD; ++k) acc += head[br2][k] * wor[k];
        out[br2 * BB * DD + b * DD + j] = acc * inv;
    }
}

extern "C" void kernel_launch(void* const* d_in, const int* in_sizes, int n_in,
                              void* d_out, int out_size, void* d_ws, size_t ws_size,
                              hipStream_t stream) {
    const float* h     = (const float*)d_in[0];
    const float* adj   = (const float*)d_in[1];
    const int*   phone = (const int*)d_in[2];
    const float* Wq_bf = (const float*)d_in[3];
    const float* Wk_bf = (const float*)d_in[4];
    const float* Wv_bf = (const float*)d_in[5];
    const float* Wo_bf = (const float*)d_in[6];
    const float* Wq_af = (const float*)d_in[7];
    const float* Wk_af = (const float*)d_in[8];
    const float* Wv_af = (const float*)d_in[9];
    const float* Wo_af = (const float*)d_in[10];

    float* out = (float*)d_out;
    float* ws  = (float*)d_ws;

    // largest compile-time P whose partial region fits ws
    int P = 16;
    while (P > 1 && (size_t)BB * P * PSTRIDE * sizeof(float) > ws_size) P >>= 1;

    switch (P) {
    case 16:
        attn_main<16><<<BB * 16, 256, 0, stream>>>(h, adj, phone, Wq_bf, Wk_bf, Wq_af, Wk_af, ws);
        finalize_kernel<16><<<BB, 256, 0, stream>>>(Wv_bf, Wo_bf, Wv_af, Wo_af, ws, out);
        break;
    case 8:
        attn_main<8><<<BB * 8, 256, 0, stream>>>(h, adj, phone, Wq_bf, Wk_bf, Wq_af, Wk_af, ws);
        finalize_kernel<8><<<BB, 256, 0, stream>>>(Wv_bf, Wo_bf, Wv_af, Wo_af, ws, out);
        break;
    case 4:
        attn_main<4><<<BB * 4, 256, 0, stream>>>(h, adj, phone, Wq_bf, Wk_bf, Wq_af, Wk_af, ws);
        finalize_kernel<4><<<BB, 256, 0, stream>>>(Wv_bf, Wo_bf, Wv_af, Wo_af, ws, out);
        break;
    case 2:
        attn_main<2><<<BB * 2, 256, 0, stream>>>(h, adj, phone, Wq_bf, Wk_bf, Wq_af, Wk_af, ws);
        finalize_kernel<2><<<BB, 256, 0, stream>>>(Wv_bf, Wo_bf, Wv_af, Wo_af, ws, out);
        break;
    default:
        attn_main<1><<<BB, 256, 0, stream>>>(h, adj, phone, Wq_bf, Wk_bf, Wq_af, Wk_af, ws);
        finalize_kernel<1><<<BB, 256, 0, stream>>>(Wv_bf, Wo_bf, Wv_af, Wo_af, ws, out);
        break;
    }
}

// Round 8
// 17.508 us; speedup vs baseline: 5.5188x; 1.0947x over previous
//
#include <hip/hip_runtime.h>
#include <math.h>

#define BB 64
#define NN 2048
#define DD 128
#define KD 16
#define NORMF 0.25f
#define CHUNK 32
#define PSTRIDE 260                 // per-block partial: 2*DD + 2 + pad

// wave-local LDS fence: DS ops within a wave are in-order; drain before cross-lane reads.
__device__ __forceinline__ void wave_lds_fence() {
    asm volatile("s_waitcnt lgkmcnt(0)" ::: "memory");
    __builtin_amdgcn_wave_barrier();
}

// ---------------- main: prologue + masked streaming over h, partials -> ws ----------------
// Issue order: adj -> h_phone -> weight regs -> ballot -> ALL h-row loads -> prologue GEMVs
// (so both HBM round trips hide under the prologue compute).
template <int P>
__global__ __launch_bounds__(256, 2)
void attn_main(const float* __restrict__ h,
               const float* __restrict__ adj,
               const int*   __restrict__ phone,
               const float* __restrict__ Wq_bf, const float* __restrict__ Wk_bf,
               const float* __restrict__ Wq_af, const float* __restrict__ Wk_af,
               float* __restrict__ ws)
{
    constexpr int K = 16 / P;          // chunks per wave (2 on the main path)
    const int tid  = threadIdx.x;
    const int wid  = tid >> 6;
    const int lane = tid & 63;
    const int half = lane >> 5;
    const int l    = lane & 31;
    const int dbase = 4 * l;

    // XCD swizzle: all P blocks of a batch on one XCD
    const int xcd  = blockIdx.x & 7;
    const int slot = blockIdx.x >> 3;
    const int b    = xcd + 8 * (slot / P);
    const int bip  = slot % P;
    const int ph   = phone[b];

    __shared__ float hp[DD];
    __shared__ float qpart[32][8];
    __shared__ float q[2][KD];
    __shared__ float w_s[2][DD];
    __shared__ float part[4][CHUNK][33];
    __shared__ float ea_s[4][CHUNK];
    __shared__ float red_h[4][2][DD];
    __shared__ float red_s[4][2];

    const float* hb     = h + (size_t)b * NN * DD;
    const float* adjrow = adj + ((size_t)b * NN + ph) * NN;
    const int chbase    = (bip * 4 + wid) * K;

    // ---- (1) adjacency loads for all K chunks
    float adjv[K];
    #pragma unroll
    for (int c = 0; c < K; ++c) adjv[c] = adjrow[(chbase + c) * CHUNK + l];

    // ---- (2) h_phone
    if (tid < DD) hp[tid] = hb[(size_t)ph * DD + tid];

    // ---- (3) weight slices into registers (removes global loads from the GEMV chains)
    const int pair = tid >> 3, sub = tid & 7;       // q-GEMV role: (br,k) x 8-way d-split
    const int brq = pair >> 4, kq = pair & 15;
    const float* Wq = brq ? Wq_af : Wq_bf;
    float wqr[16];
    #pragma unroll
    for (int i = 0; i < 16; ++i) wqr[i] = Wq[(sub * 16 + i) * KD + kq];

    const int brw = tid >> 7, dw = tid & 127;       // w-GEMV role: (br,d)
    const float* Wk = brw ? Wk_af : Wk_bf;
    float wkr[KD];
    #pragma unroll
    for (int k = 0; k < KD; ++k) wkr[k] = Wk[dw * KD + k];

    // ---- (4) ballots (waits only on adjv) + issue ALL h-row loads for the first pair
    auto load_chunk = [&](float4* hv, unsigned long long mask, int n0) {
        #pragma unroll
        for (int t = 0; t < 16; ++t) {
            const int r = 2 * t + half;
            hv[t] = make_float4(0.f, 0.f, 0.f, 0.f);
            if ((mask >> r) & 1ull)      // wave-uniform branch
                hv[t] = *(const float4*)(hb + (size_t)(n0 + r) * DD + dbase);
        }
    };

    float4 hv0[16], hv1[16];
    {
        const unsigned long long m0 = __ballot(adjv[0] != 0.f);
        load_chunk(hv0, m0, (chbase + 0) * CHUNK);
        if (K > 1) {
            const unsigned long long m1 = __ballot(adjv[1] != 0.f);
            load_chunk(hv1, m1, (chbase + 1) * CHUNK);
        }
    }

    // ---- (5) prologue GEMV chain (pure reg/LDS compute; HBM traffic in flight)
    __syncthreads();                                 // hp ready
    {
        float acc = 0.f;
        #pragma unroll
        for (int i = 0; i < 16; ++i) acc += hp[sub * 16 + i] * wqr[i];
        qpart[pair][sub] = acc;
    }
    __syncthreads();
    if (tid < 32) {
        float acc = 0.f;
        #pragma unroll
        for (int i = 0; i < 8; ++i) acc += qpart[tid][i];
        q[tid >> 4][tid & 15] = acc;
    }
    __syncthreads();
    {
        float acc = 0.f;
        #pragma unroll
        for (int k = 0; k < KD; ++k) acc += wkr[k] * q[brw][k];
        w_s[brw][dw] = NORMF * acc;
    }
    __syncthreads();

    const float4 wbf = *(const float4*)(&w_s[0][dbase]);
    const float4 waf = *(const float4*)(&w_s[1][dbase]);

    float sbf = 0.f, saf = 0.f;
    float hgbf[4] = {0, 0, 0, 0}, hgaf[4] = {0, 0, 0, 0};

    auto compute_chunk = [&](int n0, const float4* hv, float adjc) {
        // phase A: per-lane partial dots -> LDS transpose (wave-private)
        #pragma unroll
        for (int t = 0; t < 16; ++t) {
            const int r = 2 * t + half;
            const float4 w = ((n0 + r) >= ph) ? waf : wbf;
            part[wid][r][l] = hv[t].x * w.x + hv[t].y * w.y + hv[t].z * w.z + hv[t].w * w.w;
        }
        wave_lds_fence();

        // phase B: one row per lane (halves duplicate rows 0..31)
        float a0 = 0.f, a1 = 0.f, a2 = 0.f, a3 = 0.f;
        #pragma unroll
        for (int j = 0; j < 32; j += 4) {
            a0 += part[wid][l][j];
            a1 += part[wid][l][j + 1];
            a2 += part[wid][l][j + 2];
            a3 += part[wid][l][j + 3];
        }
        const float p = (a0 + a1) + (a2 + a3);
        const float e = __expf(10.f * tanhf(p) - 10.f);   // fixed max: compat in (-10,10)
        const float es = (adjc != 0.f) ? e : 0.f;
        const float ea = es * adjc;
        const bool rowaf = (n0 + l) >= ph;
        sbf += rowaf ? 0.f : es;
        saf += rowaf ? es : 0.f;
        if (lane < 32) ea_s[wid][l] = ea;
        wave_lds_fence();

        // phase C: weighted accumulation from registers
        #pragma unroll
        for (int t = 0; t < 16; ++t) {
            const int r = 2 * t + half;
            const float ear = ea_s[wid][r];               // broadcast read
            const bool af = (n0 + r) >= ph;
            const float eb = af ? 0.f : ear;
            const float ef = af ? ear : 0.f;
            hgbf[0] += eb * hv[t].x; hgbf[1] += eb * hv[t].y;
            hgbf[2] += eb * hv[t].z; hgbf[3] += eb * hv[t].w;
            hgaf[0] += ef * hv[t].x; hgaf[1] += ef * hv[t].y;
            hgaf[2] += ef * hv[t].z; hgaf[3] += ef * hv[t].w;
        }
    };

    // ---- (6) compute the first (preloaded) pair
    compute_chunk((chbase + 0) * CHUNK, hv0, adjv[0]);
    if (K > 1) compute_chunk((chbase + 1) * CHUNK, hv1, adjv[1]);

    // ---- remaining pairs (fallback paths K>2 only)
    #pragma unroll
    for (int cc = 2; cc < K; cc += 2) {
        const unsigned long long m0 = __ballot(adjv[cc] != 0.f);
        load_chunk(hv0, m0, (chbase + cc) * CHUNK);
        if (cc + 1 < K) {
            const unsigned long long m1 = __ballot(adjv[cc + 1] != 0.f);
            load_chunk(hv1, m1, (chbase + cc + 1) * CHUNK);
        }
        compute_chunk((chbase + cc) * CHUNK, hv0, adjv[cc]);
        if (cc + 1 < K) compute_chunk((chbase + cc + 1) * CHUNK, hv1, adjv[cc + 1]);
    }

    // ---- per-wave reductions
    #pragma unroll
    for (int m = 1; m <= 16; m <<= 1) {
        sbf += __shfl_xor(sbf, m, 64);
        saf += __shfl_xor(saf, m, 64);
    }
    #pragma unroll
    for (int i = 0; i < 4; ++i) {
        hgbf[i] += __shfl_xor(hgbf[i], 32, 64);   // combine halves (same d-range)
        hgaf[i] += __shfl_xor(hgaf[i], 32, 64);
    }
    if (lane < 32) {
        #pragma unroll
        for (int i = 0; i < 4; ++i) {
            red_h[wid][0][dbase + i] = hgbf[i];
            red_h[wid][1][dbase + i] = hgaf[i];
        }
    }
    if (lane == 0) { red_s[wid][0] = sbf; red_s[wid][1] = saf; }
    __syncthreads();   // the only cross-wave exchange

    {   // block partial -> ws (coalesced, no atomics, no fences)
        const int br = tid >> 7, d = tid & 127;
        float* op = ws + (size_t)(b * P + bip) * PSTRIDE;
        op[br * DD + d] = red_h[0][br][d] + red_h[1][br][d] + red_h[2][br][d] + red_h[3][br][d];
        if (tid < 2)
            op[2 * DD + tid] = red_s[0][tid] + red_s[1][tid] + red_s[2][tid] + red_s[3][tid];
    }
}

// ---------------- finalize: reduce P partials, head = hagg@Wv, out = (head@Wo)/s ----
template <int P>
__global__ __launch_bounds__(256)
void finalize_kernel(const float* __restrict__ Wv_bf, const float* __restrict__ Wo_bf,
                     const float* __restrict__ Wv_af, const float* __restrict__ Wo_af,
                     const float* __restrict__ ws, float* __restrict__ out)
{
    const int b = blockIdx.x;
    const int tid = threadIdx.x;
    __shared__ float hs[2][DD];
    __shared__ float ssum[2];
    __shared__ float hpart[32][8];
    __shared__ float head[2][KD];

    // issue ALL independent loads up front
    const int pair = tid >> 3, sub = tid & 7;
    const int brv = pair >> 4, kv = pair & 15;
    const float* Wv = brv ? Wv_af : Wv_bf;
    float wvr[16];
    #pragma unroll
    for (int i = 0; i < 16; ++i) wvr[i] = Wv[(sub * 16 + i) * KD + kv];

    const int br2 = tid >> 7, j = tid & 127;
    const float* Wo = br2 ? Wo_af : Wo_bf;
    float wor[KD];
    #pragma unroll
    for (int k = 0; k < KD; ++k) wor[k] = Wo[k * DD + j];

    const float* base = ws + (size_t)b * P * PSTRIDE;
    {
        float acc = 0.f;
        #pragma unroll
        for (int p = 0; p < P; ++p) acc += base[(size_t)p * PSTRIDE + br2 * DD + j];
        hs[br2][j] = acc;
    }
    if (tid < 2) {
        float acc = 0.f;
        #pragma unroll
        for (int p = 0; p < P; ++p) acc += base[(size_t)p * PSTRIDE + 2 * DD + tid];
        ssum[tid] = acc;
    }
    __syncthreads();

    {
        float acc = 0.f;
        #pragma unroll
        for (int i = 0; i < 16; ++i) acc += hs[brv][sub * 16 + i] * wvr[i];
        hpart[pair][sub] = acc;
    }
    __syncthreads();
    if (tid < 32) {
        float acc = 0.f;
        #pragma unroll
        for (int i = 0; i < 8; ++i) acc += hpart[tid][i];
        head[tid >> 4][tid & 15] = acc;
    }
    __syncthreads();

    {
        const float s = ssum[br2];
        const float inv = (s > 0.f) ? 1.f / s : 0.f;
        float acc = 0.f;
        #pragma unroll
        for (int k = 0; k < KD; ++k) acc += head[br2][k] * wor[k];
        out[br2 * BB * DD + b * DD + j] = acc * inv;
    }
}

extern "C" void kernel_launch(void* const* d_in, const int* in_sizes, int n_in,
                              void* d_out, int out_size, void* d_ws, size_t ws_size,
                              hipStream_t stream) {
    const float* h     = (const float*)d_in[0];
    const float* adj   = (const float*)d_in[1];
    const int*   phone = (const int*)d_in[2];
    const float* Wq_bf = (const float*)d_in[3];
    const float* Wk_bf = (const float*)d_in[4];
    const float* Wv_bf = (const float*)d_in[5];
    const float* Wo_bf = (const float*)d_in[6];
    const float* Wq_af = (const float*)d_in[7];
    const float* Wk_af = (const float*)d_in[8];
    const float* Wv_af = (const float*)d_in[9];
    const float* Wo_af = (const float*)d_in[10];

    float* out = (float*)d_out;
    float* ws  = (float*)d_ws;

    // largest compile-time P (<=8) whose partial region fits ws
    int P = 8;
    while (P > 1 && (size_t)BB * P * PSTRIDE * sizeof(float) > ws_size) P >>= 1;

    switch (P) {
    case 8:
        attn_main<8><<<BB * 8, 256, 0, stream>>>(h, adj, phone, Wq_bf, Wk_bf, Wq_af, Wk_af, ws);
        finalize_kernel<8><<<BB, 256, 0, stream>>>(Wv_bf, Wo_bf, Wv_af, Wo_af, ws, out);
        break;
    case 4:
        attn_main<4><<<BB * 4, 256, 0, stream>>>(h, adj, phone, Wq_bf, Wk_bf, Wq_af, Wk_af, ws);
        finalize_kernel<4><<<BB, 256, 0, stream>>>(Wv_bf, Wo_bf, Wv_af, Wo_af, ws, out);
        break;
    case 2:
        attn_main<2><<<BB * 2, 256, 0, stream>>>(h, adj, phone, Wq_bf, Wk_bf, Wq_af, Wk_af, ws);
        finalize_kernel<2><<<BB, 256, 0, stream>>>(Wv_bf, Wo_bf, Wv_af, Wo_af, ws, out);
        break;
    default:
        attn_main<1><<<BB, 256, 0, stream>>>(h, adj, phone, Wq_bf, Wk_bf, Wq_af, Wk_af, ws);
        finalize_kernel<1><<<BB, 256, 0, stream>>>(Wv_bf, Wo_bf, Wv_af, Wo_af, ws, out);
        break;
    }
}